// Round 5
// baseline (73.910 us; speedup 1.0000x reference)
//
#include <hip/hip_runtime.h>
#include <float.h>
#include <math.h>

// Problem constants (fixed by reference)
#define NB    8
#define K1    2048
#define K2    8192
#define NADD  16
#define PP    128          // K1 / NUM_ADD
#define FEPS  1e-7f
#define CDW   0.1f

// chamfer tiling (R3 config -- best so far)
#define OCH   64           // ori chunks
#define OCLEN (K2 / OCH)   // 128 ori points per chunk
#define KC    2            // adv halves
#define MPT   4            // adv points per thread (K1/KC/256): 4 indep chains
#define CH_GRID  (OCH * KC * NB)   // 1024 chamfer blocks
#define FAR_GRID 64                // (b, cluster-pair) blocks
#define TOT_GRID (CH_GRID + FAR_GRID)  // 1088

// ws layout (uint words): [0, NB*K1) gmin ; [NB*K1] ctr ; then 128 far floats
#define GMIN_WORDS (NB * K1)       // 16384 words = 64 KB
#define CTR_IDX    GMIN_WORDS
#define FARW_IDX   (GMIN_WORDS + 1)

// ---------------------------------------------------------------------------
// Single fused kernel:
//   blocks [0, CH_GRID)          : chamfer partial min -> atomicMin into gmin
//   blocks [CH_GRID, TOT_GRID)   : farthest pairwise dist per cluster pair
//   last block to finish (atomic counter) : final weighted combine -> out[0]
// gmin holds clamped d^2 as uint bits; values are >= 0 so uint order == float
// order and atomicMin is exact and order-independent (deterministic).
// ---------------------------------------------------------------------------
__global__ __launch_bounds__(256) void fused_all(const float* __restrict__ adv,
                                                 const float* __restrict__ ori,
                                                 const float* __restrict__ w,
                                                 unsigned int* __restrict__ wsw,
                                                 float* __restrict__ out) {
    __shared__ float4 s4[192];        // chamfer: 128 float4 | farthest: 768 floats
    __shared__ float sred[4];
    __shared__ unsigned int lastflag;
    unsigned int* gmin = wsw;
    unsigned int* ctr  = wsw + CTR_IDX;
    float*        far  = (float*)(wsw + FARW_IDX);
    const int bid = blockIdx.x;
    const int t   = threadIdx.x;

    if (bid < CH_GRID) {
        // ---- chamfer partial: ori chunk oc of batch b vs adv half kc ----
        const int oc = bid & (OCH - 1);
        const int kc = (bid >> 6) & (KC - 1);
        const int b  = bid >> 7;

        if (t < OCLEN) {               // stage + pack [x,y,z,|o|^2]
            const float* o = ori + ((size_t)b * K2 + oc * OCLEN + t) * 3;
            float x = o[0], y = o[1], z = o[2];
            s4[t] = make_float4(x, y, z, fmaf(x, x, fmaf(y, y, z * z)));
        }
        __syncthreads();

        float bx[MPT], by[MPT], bz[MPT], a2[MPT], dmin[MPT];
        const int k0 = kc * (K1 / KC) + t;
#pragma unroll
        for (int j = 0; j < MPT; ++j) {
            const float* a = adv + (size_t)(b * K1 + k0 + 256 * j) * 3;
            float ax = a[0], ay = a[1], az = a[2];
            bx[j] = -2.f * ax; by[j] = -2.f * ay; bz[j] = -2.f * az;
            a2[j] = fmaf(ax, ax, fmaf(ay, ay, az * az));
            dmin[j] = FLT_MAX;
        }

#pragma unroll 8
        for (int m = 0; m < OCLEN; ++m) {
            float4 o = s4[m];          // uniform address -> LDS broadcast
#pragma unroll
            for (int j = 0; j < MPT; ++j)
                dmin[j] = fminf(dmin[j],
                                fmaf(bx[j], o.x, fmaf(by[j], o.y, fmaf(bz[j], o.z, o.w))));
        }

#pragma unroll
        for (int j = 0; j < MPT; ++j) {
            // clamp commutes with min; non-negative -> uint-order == float-order
            float v = fmaxf(a2[j] + dmin[j], 0.f);
            atomicMin(&gmin[b * K1 + k0 + 256 * j], __float_as_uint(v));
        }
    } else {
        // ---- farthest: block = (b, cluster-pair), 128 threads per cluster ----
        const int fb = bid - CH_GRID;
        const int b  = fb >> 3;
        const int cp = fb & 7;
        const int g  = t >> 7;        // which cluster of the pair
        const int p  = t & 127;
        const int ci = cp * 2 + g;

        float* sf = (float*)s4;       // [2][3][128]
        const float* c = adv + (size_t)(b * K1 + ci * PP) * 3;
        float px = c[p * 3 + 0], py = c[p * 3 + 1], pz = c[p * 3 + 2];
        float* sx = sf + g * 384;
        sx[p] = px; sx[128 + p] = py; sx[256 + p] = pz;
        __syncthreads();

        const float pxm = px - FEPS, pym = py - FEPS, pzm = pz - FEPS;
        float mx = 0.f;
#pragma unroll 8
        for (int q = 0; q < PP; ++q) {
            float dx = sx[q] - pxm;
            float dy = sx[128 + q] - pym;
            float dz = sx[256 + q] - pzm;
            mx = fmaxf(mx, fmaf(dx, dx, fmaf(dy, dy, dz * dz)));
        }
#pragma unroll
        for (int off = 32; off; off >>= 1) mx = fmaxf(mx, __shfl_down(mx, off, 64));
        if ((t & 63) == 0) sred[t >> 6] = mx;
        __syncthreads();
        if (t == 0)
            __hip_atomic_store(&far[b * NADD + cp * 2 + 0],
                               sqrtf(fmaxf(sred[0], sred[1])),
                               __ATOMIC_RELEASE, __HIP_MEMORY_SCOPE_AGENT);
        if (t == 128)
            __hip_atomic_store(&far[b * NADD + cp * 2 + 1],
                               sqrtf(fmaxf(sred[2], sred[3])),
                               __ATOMIC_RELEASE, __HIP_MEMORY_SCOPE_AGENT);
    }

    // ---- completion counter; last block (of all TOT_GRID) finalizes ----
    __syncthreads();                   // drains each block's vmem before signaling
    if (t == 0) {
        unsigned int old = __hip_atomic_fetch_add(ctr, 1u,
                            __ATOMIC_ACQ_REL, __HIP_MEMORY_SCOPE_AGENT);
        // ctr was memset to 0xFFFFFFFF: returns are 0xFFFFFFFF, 0, 1, ...,
        // so the TOT_GRID-th arrival sees TOT_GRID-2.
        lastflag = (old == (unsigned int)(TOT_GRID - 2)) ? 1u : 0u;
    }
    __syncthreads();
    if (!lastflag) return;

    // ---- final combine (single block, fixed order -> deterministic) ----
    float v;
    {
        const int b = t >> 5, l = t & 31;   // 32 threads per batch
        float csum = 0.f;
#pragma unroll 8
        for (int i = 0; i < K1 / 32; ++i)   // coalesced, L2-resident
            csum += __uint_as_float(__hip_atomic_load(&gmin[b * K1 + l + 32 * i],
                        __ATOMIC_ACQUIRE, __HIP_MEMORY_SCOPE_AGENT));
        v = csum * w[b] * (CDW * 0.125f / K1);
        if (t < 128) {
            float fw = __uint_as_float(__hip_atomic_load((unsigned int*)&far[t],
                        __ATOMIC_ACQUIRE, __HIP_MEMORY_SCOPE_AGENT));
            v = fmaf(w[t >> 4] * 0.125f, fw, v);
        }
    }
#pragma unroll
    for (int off = 32; off; off >>= 1) v += __shfl_down(v, off, 64);
    __syncthreads();                  // s4/sred reuse safety
    if ((t & 63) == 0) sred[t >> 6] = v;
    __syncthreads();
    if (t == 0) out[0] = sred[0] + sred[1] + sred[2] + sred[3];
}

// ---------------------------------------------------------------------------
extern "C" void kernel_launch(void* const* d_in, const int* in_sizes, int n_in,
                              void* d_out, int out_size, void* d_ws, size_t ws_size,
                              hipStream_t stream) {
    const float* adv = (const float*)d_in[0];
    const float* ori = (const float*)d_in[1];
    const float* w   = (const float*)d_in[2];
    unsigned int* wsw = (unsigned int*)d_ws;
    float* out = (float*)d_out;

    // gmin := +inf (as uint bits), ctr := 0xFFFFFFFF -- one small blit
    hipMemsetAsync(wsw, 0xFF, (GMIN_WORDS + 1) * sizeof(unsigned int), stream);
    fused_all<<<dim3(TOT_GRID), 256, 0, stream>>>(adv, ori, w, wsw, out);
}

// Round 6
// 52.170 us; speedup vs baseline: 1.4167x; 1.4167x over previous
//
#include <hip/hip_runtime.h>
#include <float.h>
#include <math.h>

// Problem constants (fixed by reference)
#define NB    8
#define K1    2048
#define K2    8192
#define NADD  16
#define PP    128          // K1 / NUM_ADD
#define FEPS  1e-7f
#define CDW   0.1f

// chamfer tiling: no LDS staging; ori chunk read via uniform (scalar) loads.
// grid 1024 chamfer blocks = 4 blocks/CU = 16 waves/CU; 8 indep chains/thread.
#define OCH   128          // ori chunks
#define OCLEN (K2 / OCH)   // 64 ori points per chunk
#define MPT   8            // adv points per thread (K1/256): 8 indep min chains
#define CH_GRID  (OCH * NB)        // 1024 chamfer blocks
#define FAR_GRID 64                // (b, cluster-pair) blocks
#define GRID_A   (CH_GRID + FAR_GRID)

// reduce grid
#define RB_GRID 64                 // (kc 0..7) x (b 0..7)

// ws layout (float offsets)
#define PMIN_OFF 0
#define PMIN_SZ  (OCH * NB * K1)          // 2,097,152 floats (8 MB)
#define FARW_OFF PMIN_SZ
#define CHB_OFF  (FARW_OFF + NB * NADD)
#define CTR_OFF  (CHB_OFF + RB_GRID)

// ---------------------------------------------------------------------------
// Kernel A: fused chamfer-partial (blocks 0..1023) + farthest (1024..1087).
// Chamfer: each block = (oc, b); all 256 threads scan the same 64 ori points
// through SGPR broadcasts (uniform loads), each thread owns 8 adv points.
// Per iter per thread: 3 VALU for |o|^2 + 8 x (3 fma + 1 min) = 35 VALU,
// zero LDS traffic.
// ---------------------------------------------------------------------------
__global__ __launch_bounds__(256) void fused_a(const float* __restrict__ adv,
                                               const float* __restrict__ ori,
                                               float* __restrict__ pmins,
                                               float* __restrict__ far,
                                               unsigned int* __restrict__ ctr) {
    __shared__ float sf[768];         // farthest path only
    __shared__ float sred[4];
    const int bid = blockIdx.x;
    const int t   = threadIdx.x;
    if (bid == 0 && t == 0) *ctr = 0u;   // reset kernel-B completion counter

    if (bid < CH_GRID) {
        // ---- chamfer partial: ori chunk oc of batch b ----
        const int oc = bid & (OCH - 1);
        const int b  = bid >> 7;

        float bx[MPT], by[MPT], bz[MPT], dmin[MPT];
#pragma unroll
        for (int j = 0; j < MPT; ++j) {
            const float* a = adv + (size_t)(b * K1 + t + 256 * j) * 3;
            bx[j] = -2.f * a[0];
            by[j] = -2.f * a[1];
            bz[j] = -2.f * a[2];
            dmin[j] = FLT_MAX;
        }

        // block-uniform base -> compiler proves uniformity -> s_load broadcasts
        const float* o = ori + ((size_t)b * K2 + (size_t)oc * OCLEN) * 3;
#pragma unroll 4
        for (int m = 0; m < OCLEN; ++m) {
            float ox = o[3 * m + 0];
            float oy = o[3 * m + 1];
            float oz = o[3 * m + 2];
            float o2 = fmaf(ox, ox, fmaf(oy, oy, oz * oz));
#pragma unroll
            for (int j = 0; j < MPT; ++j)
                dmin[j] = fminf(dmin[j],
                                fmaf(bx[j], ox, fmaf(by[j], oy, fmaf(bz[j], oz, o2))));
        }

#pragma unroll
        for (int j = 0; j < MPT; ++j)  // coalesced
            pmins[((size_t)oc * NB + b) * K1 + t + 256 * j] = dmin[j];
    } else {
        // ---- farthest: block = (b, cluster-pair), 128 threads per cluster ----
        const int fb = bid - CH_GRID;
        const int b  = fb >> 3;
        const int cp = fb & 7;
        const int g  = t >> 7;        // which cluster of the pair
        const int p  = t & 127;
        const int ci = cp * 2 + g;

        const float* c = adv + (size_t)(b * K1 + ci * PP) * 3;
        float px = c[p * 3 + 0], py = c[p * 3 + 1], pz = c[p * 3 + 2];
        float* sx = sf + g * 384;
        sx[p] = px; sx[128 + p] = py; sx[256 + p] = pz;
        __syncthreads();

        const float pxm = px - FEPS, pym = py - FEPS, pzm = pz - FEPS;
        float mx = 0.f;
#pragma unroll 8
        for (int q = 0; q < PP; ++q) {
            float dx = sx[q] - pxm;
            float dy = sx[128 + q] - pym;
            float dz = sx[256 + q] - pzm;
            mx = fmaxf(mx, fmaf(dx, dx, fmaf(dy, dy, dz * dz)));
        }
#pragma unroll
        for (int off = 32; off; off >>= 1) mx = fmaxf(mx, __shfl_down(mx, off, 64));
        if ((t & 63) == 0) sred[t >> 6] = mx;
        __syncthreads();
        if (t == 0)   far[b * NADD + cp * 2 + 0] = sqrtf(fmaxf(sred[0], sred[1]));
        if (t == 128) far[b * NADD + cp * 2 + 1] = sqrtf(fmaxf(sred[2], sred[3]));
    }
}

// ---------------------------------------------------------------------------
// Kernel B: min over 128 chunks + a^2 + clamp + per-(b,kc) sum; last-done
// block does the final weighted combine. grid 64 x 256 thr.
// ---------------------------------------------------------------------------
__global__ __launch_bounds__(256) void reduce_b(const float* __restrict__ adv,
                                                const float* __restrict__ pmins,
                                                const float* __restrict__ far,
                                                const float* __restrict__ w,
                                                float* __restrict__ chbp,
                                                unsigned int* __restrict__ ctr,
                                                float* __restrict__ out) {
    __shared__ float s[4];
    __shared__ unsigned int lastflag;
    const int t  = threadIdx.x;
    const int kc = blockIdx.x & 7;
    const int b  = blockIdx.x >> 3;
    const int k  = kc * 256 + t;

    float m = FLT_MAX;
#pragma unroll 8
    for (int oc = 0; oc < OCH; ++oc)   // coalesced across threads each iter
        m = fminf(m, pmins[((size_t)oc * NB + b) * K1 + k]);

    const float* a = adv + (size_t)(b * K1 + k) * 3;
    float ax = a[0], ay = a[1], az = a[2];
    float a2 = fmaf(ax, ax, fmaf(ay, ay, az * az));
    float sum = fmaxf(a2 + m, 0.f);

#pragma unroll
    for (int off = 32; off; off >>= 1) sum += __shfl_down(sum, off, 64);
    const int lane = t & 63, wid = t >> 6;
    if (lane == 0) s[wid] = sum;
    __syncthreads();

    if (t == 0) {
        float part = s[0] + s[1] + s[2] + s[3];
        __hip_atomic_store(&chbp[b * 8 + kc], part,
                           __ATOMIC_RELEASE, __HIP_MEMORY_SCOPE_AGENT);
        unsigned int old = __hip_atomic_fetch_add(ctr, 1u,
                           __ATOMIC_ACQ_REL, __HIP_MEMORY_SCOPE_AGENT);
        lastflag = (old == RB_GRID - 1) ? 1u : 0u;
    }
    __syncthreads();
    if (!lastflag) return;

    // ---- final combine (single block, fixed order -> deterministic) ----
    float v = 0.f;
    if (t < 128) v = w[t >> 4] * far[t] * 0.125f;
    if (t < 64)
        v += (CDW * 0.125f / K1) * w[t >> 3] *
             __hip_atomic_load(&chbp[t], __ATOMIC_ACQUIRE, __HIP_MEMORY_SCOPE_AGENT);
#pragma unroll
    for (int off = 32; off; off >>= 1) v += __shfl_down(v, off, 64);
    __syncthreads();                 // protect s[] reuse
    if (lane == 0) s[wid] = v;
    __syncthreads();
    if (t == 0) out[0] = s[0] + s[1] + s[2] + s[3];
}

// ---------------------------------------------------------------------------
extern "C" void kernel_launch(void* const* d_in, const int* in_sizes, int n_in,
                              void* d_out, int out_size, void* d_ws, size_t ws_size,
                              hipStream_t stream) {
    const float* adv = (const float*)d_in[0];
    const float* ori = (const float*)d_in[1];
    const float* w   = (const float*)d_in[2];
    float* ws    = (float*)d_ws;
    float* pmins = ws + PMIN_OFF;
    float* far   = ws + FARW_OFF;
    float* chbp  = ws + CHB_OFF;
    unsigned int* ctr = (unsigned int*)(ws + CTR_OFF);
    float* out   = (float*)d_out;

    fused_a<<<dim3(GRID_A), 256, 0, stream>>>(adv, ori, pmins, far, ctr);
    reduce_b<<<dim3(RB_GRID), 256, 0, stream>>>(adv, pmins, far, w, chbp, ctr, out);
}

// Round 7
// 40.943 us; speedup vs baseline: 1.8052x; 1.2742x over previous
//
#include <hip/hip_runtime.h>
#include <float.h>
#include <math.h>

// Problem constants (fixed by reference)
#define NB    8
#define K1    2048
#define K2    8192
#define NADD  16
#define PP    128          // K1 / NUM_ADD
#define FEPS  1e-7f
#define CDW   0.1f

// chamfer tiling: LDS-staged ori chunks, 8 independent min chains per thread.
// Per inner iter: 1 uniform ds_read_b128 -> 32 VALU ops (LDS pipe no longer
// binding: ~5.5us/CU LDS vs ~7.3us/CU VALU).
#define OCH   128          // ori chunks
#define OCLEN (K2 / OCH)   // 64 ori points per chunk
#define MPT   8            // adv points per thread (K1/256): 8 indep min chains
#define CH_GRID  (OCH * NB)        // 1024 chamfer blocks = 4 blocks/CU
#define FAR_GRID 64                // (b, cluster-pair) blocks
#define GRID_A   (CH_GRID + FAR_GRID)

// reduce grid: 256 blocks, each owns 64 adv points x all 128 chunks
#define RB_KB 32           // k-blocks per batch (64 points each)
#define RB_GRID (RB_KB * NB)       // 256 blocks

// ws layout (float offsets)
#define PMIN_OFF 0
#define PMIN_SZ  (OCH * NB * K1)          // 2,097,152 floats (8 MB)
#define FARW_OFF PMIN_SZ
#define CHB_OFF  (FARW_OFF + NB * NADD)
#define CTR_OFF  (CHB_OFF + RB_GRID)

// ---------------------------------------------------------------------------
// Kernel A: fused chamfer-partial (blocks 0..1023) + farthest (1024..1087)
// ---------------------------------------------------------------------------
__global__ __launch_bounds__(256) void fused_a(const float* __restrict__ adv,
                                               const float* __restrict__ ori,
                                               float* __restrict__ pmins,
                                               float* __restrict__ far,
                                               unsigned int* __restrict__ ctr) {
    __shared__ float4 s4[192];        // chamfer: 64 float4 | farthest: 768 floats
    __shared__ float sred[4];
    const int bid = blockIdx.x;
    const int t   = threadIdx.x;
    if (bid == 0 && t == 0) *ctr = 0u;   // reset kernel-B counter (B runs after A)

    if (bid < CH_GRID) {
        // ---- chamfer partial: ori chunk oc of batch b ----
        const int oc = bid & (OCH - 1);
        const int b  = bid >> 7;

        if (t < OCLEN) {               // stage + pack [x,y,z,|o|^2]
            const float* o = ori + ((size_t)b * K2 + oc * OCLEN + t) * 3;
            float x = o[0], y = o[1], z = o[2];
            s4[t] = make_float4(x, y, z, fmaf(x, x, fmaf(y, y, z * z)));
        }

        float bx[MPT], by[MPT], bz[MPT], dmin[MPT];
#pragma unroll
        for (int j = 0; j < MPT; ++j) {
            const float* a = adv + (size_t)(b * K1 + t + 256 * j) * 3;
            bx[j] = -2.f * a[0];
            by[j] = -2.f * a[1];
            bz[j] = -2.f * a[2];
            dmin[j] = FLT_MAX;
        }
        __syncthreads();

#pragma unroll 4
        for (int m = 0; m < OCLEN; ++m) {
            float4 o = s4[m];          // uniform address -> LDS broadcast
#pragma unroll
            for (int j = 0; j < MPT; ++j)
                dmin[j] = fminf(dmin[j],
                                fmaf(bx[j], o.x, fmaf(by[j], o.y, fmaf(bz[j], o.z, o.w))));
        }

#pragma unroll
        for (int j = 0; j < MPT; ++j)  // coalesced
            pmins[((size_t)oc * NB + b) * K1 + t + 256 * j] = dmin[j];
    } else {
        // ---- farthest: block = (b, cluster-pair), 128 threads per cluster ----
        const int fb = bid - CH_GRID;
        const int b  = fb >> 3;
        const int cp = fb & 7;
        const int g  = t >> 7;        // which cluster of the pair
        const int p  = t & 127;
        const int ci = cp * 2 + g;

        float* sf = (float*)s4;       // [2][3][128]
        const float* c = adv + (size_t)(b * K1 + ci * PP) * 3;
        float px = c[p * 3 + 0], py = c[p * 3 + 1], pz = c[p * 3 + 2];
        float* sx = sf + g * 384;
        sx[p] = px; sx[128 + p] = py; sx[256 + p] = pz;
        __syncthreads();

        const float pxm = px - FEPS, pym = py - FEPS, pzm = pz - FEPS;
        float mx = 0.f;
#pragma unroll 8
        for (int q = 0; q < PP; ++q) {
            float dx = sx[q] - pxm;
            float dy = sx[128 + q] - pym;
            float dz = sx[256 + q] - pzm;
            mx = fmaxf(mx, fmaf(dx, dx, fmaf(dy, dy, dz * dz)));
        }
#pragma unroll
        for (int off = 32; off; off >>= 1) mx = fmaxf(mx, __shfl_down(mx, off, 64));
        if ((t & 63) == 0) sred[t >> 6] = mx;
        __syncthreads();
        if (t == 0)   far[b * NADD + cp * 2 + 0] = sqrtf(fmaxf(sred[0], sred[1]));
        if (t == 128) far[b * NADD + cp * 2 + 1] = sqrtf(fmaxf(sred[2], sred[3]));
    }
}

// ---------------------------------------------------------------------------
// Kernel B: min over 128 chunks + clamp + per-(b,kb) sum; last block combines.
// grid (32, 8) x 256 thr. Block (kb,b): adv points kb*64..kb*64+63.
// Thread t: point p=t&63, oc-strip st=t>>6 (32 chunks each).
// ---------------------------------------------------------------------------
__global__ __launch_bounds__(256) void reduce_b(const float* __restrict__ adv,
                                                const float* __restrict__ pmins,
                                                const float* __restrict__ far,
                                                const float* __restrict__ w,
                                                float* __restrict__ chbp,
                                                unsigned int* __restrict__ ctr,
                                                float* __restrict__ out) {
    __shared__ float smin[4][64];
    __shared__ float s[4];
    __shared__ unsigned int lastflag;
    const int t  = threadIdx.x;
    const int kb = blockIdx.x;
    const int b  = blockIdx.y;
    const int p  = t & 63;
    const int st = t >> 6;
    const int k  = kb * 64 + p;

    float m = FLT_MAX;
#pragma unroll 8
    for (int i = 0; i < OCH / 4; ++i) {   // 32 loads, coalesced per wave
        int oc = st * (OCH / 4) + i;
        m = fminf(m, pmins[((size_t)oc * NB + b) * K1 + k]);
    }
    smin[st][p] = m;
    __syncthreads();

    float sum = 0.f;
    if (t < 64) {
        float mm = fminf(fminf(smin[0][t], smin[1][t]), fminf(smin[2][t], smin[3][t]));
        const float* a = adv + (size_t)(b * K1 + kb * 64 + t) * 3;
        float ax = a[0], ay = a[1], az = a[2];
        float a2 = fmaf(ax, ax, fmaf(ay, ay, az * az));
        sum = fmaxf(a2 + mm, 0.f);
#pragma unroll
        for (int off = 32; off; off >>= 1) sum += __shfl_down(sum, off, 64);
    }

    if (t == 0) {
        __hip_atomic_store(&chbp[b * RB_KB + kb], sum,
                           __ATOMIC_RELEASE, __HIP_MEMORY_SCOPE_AGENT);
        unsigned int old = __hip_atomic_fetch_add(ctr, 1u,
                           __ATOMIC_ACQ_REL, __HIP_MEMORY_SCOPE_AGENT);
        lastflag = (old == RB_GRID - 1) ? 1u : 0u;
    }
    __syncthreads();
    if (!lastflag) return;

    // ---- final combine (single block, fixed order -> deterministic) ----
    float v = (CDW * 0.125f / K1) * w[t >> 5] *
              __hip_atomic_load(&chbp[t], __ATOMIC_ACQUIRE, __HIP_MEMORY_SCOPE_AGENT);
    if (t < 128) v += w[t >> 4] * far[t] * 0.125f;
#pragma unroll
    for (int off = 32; off; off >>= 1) v += __shfl_down(v, off, 64);
    __syncthreads();                 // protect s[] reuse
    if ((t & 63) == 0) s[t >> 6] = v;
    __syncthreads();
    if (t == 0) out[0] = s[0] + s[1] + s[2] + s[3];
}

// ---------------------------------------------------------------------------
extern "C" void kernel_launch(void* const* d_in, const int* in_sizes, int n_in,
                              void* d_out, int out_size, void* d_ws, size_t ws_size,
                              hipStream_t stream) {
    const float* adv = (const float*)d_in[0];
    const float* ori = (const float*)d_in[1];
    const float* w   = (const float*)d_in[2];
    float* ws    = (float*)d_ws;
    float* pmins = ws + PMIN_OFF;
    float* far   = ws + FARW_OFF;
    float* chbp  = ws + CHB_OFF;
    unsigned int* ctr = (unsigned int*)(ws + CTR_OFF);
    float* out   = (float*)d_out;

    fused_a<<<dim3(GRID_A), 256, 0, stream>>>(adv, ori, pmins, far, ctr);
    reduce_b<<<dim3(RB_KB, NB), 256, 0, stream>>>(adv, pmins, far, w, chbp, ctr, out);
}